// Round 5
// baseline (383.327 us; speedup 1.0000x reference)
//
#include <hip/hip_runtime.h>
#include <math.h>

#define B_ 64
#define I_ 4096
#define P_ 8      // Din
#define N_ 10
#define D_ 16
#define ND_ 160   // N*D
#define BND_ (B_*ND_)   // 10240
#define EPS_ 1e-7f

// DPP quad_perm add: butterfly within each 4-lane quad on the VALU pipe
// (no ds_bpermute / LDS traffic). 0xB1 = [1,0,3,2] (xor1), 0x4E = [2,3,0,1] (xor2).
template<int CTRL>
__device__ __forceinline__ float qp_add(float v) {
    int r = __builtin_amdgcn_update_dpp(0, __float_as_int(v), CTRL, 0xF, 0xF, true);
    return v + __int_as_float(r);
}

// Lane mapping: lane = bl*4 + dq. bl = 0..15 (b = w*16+bl), dq = d-quad owning
// d = dq*4..dq*4+3 as float4. The logit d-reduction is a 2-step DPP quad
// butterfly -> zero LDS ops in the whole kernel (round 4 was LDS-pipe-bound:
// 160 ds_bpermute per wave-il saturated the DS pipe at 43% VALUBusy).
// Vc for this thread's (b, dq) = 10 float4 in registers, loaded once.
//
// __launch_bounds__(256, 2): allows up to 256 VGPR -> no spill (~190 expected).
// Round 3 proved tighter bounds force catastrophic scratch spill. DO NOT tighten.
template<int MODE, int IPB>
__global__ __launch_bounds__(256, 2)
void digitcaps_pass(const float* __restrict__ x, const float* __restrict__ W,
                    const float* __restrict__ Vc, float* __restrict__ part)
{
    const int t = threadIdx.x;
    const int lane = t & 63;
    const int w = t >> 6;        // wave 0..3
    const int dq = lane & 3;     // d-quad
    const int bl = lane >> 2;    // 0..15
    const int b = w * 16 + bl;

    float4 vc[N_];
    if (MODE == 1) {
#pragma unroll
        for (int n = 0; n < N_; ++n)
            vc[n] = *(const float4*)(Vc + b * ND_ + n * D_ + dq * 4);
    }

    float4 acc[N_];
#pragma unroll
    for (int n = 0; n < N_; ++n) { acc[n].x = 0.f; acc[n].y = 0.f; acc[n].z = 0.f; acc[n].w = 0.f; }

    const int i0 = blockIdx.x * IPB;

#pragma unroll
    for (int il = 0; il < IPB; ++il) {
        const int i = i0 + il;
        const float* __restrict__ Wi = W + (size_t)i * (N_ * P_ * D_) + dq * 4;

        float xv[P_];
        {
            const float4* xp = (const float4*)(x + ((size_t)b * I_ + i) * P_);
            float4 a0 = xp[0], a1 = xp[1];
            xv[0]=a0.x; xv[1]=a0.y; xv[2]=a0.z; xv[3]=a0.w;
            xv[4]=a1.x; xv[5]=a1.y; xv[6]=a1.z; xv[7]=a1.w;
        }

        float4 tv[N_];   // u_hat[b,i,n, dq*4..dq*4+3]
        float lg[N_];
#pragma unroll
        for (int n = 0; n < N_; ++n) {
            float4 s; s.x = 0.f; s.y = 0.f; s.z = 0.f; s.w = 0.f;
#pragma unroll
            for (int p = 0; p < P_; ++p) {
                // 4 dq-lanes cover one 64B row of W[i,n,p,:] -> wave reads 64B, broadcast over b-lanes
                float4 wv = *(const float4*)(Wi + (n * P_ + p) * D_);
                s.x = fmaf(xv[p], wv.x, s.x);
                s.y = fmaf(xv[p], wv.y, s.y);
                s.z = fmaf(xv[p], wv.z, s.z);
                s.w = fmaf(xv[p], wv.w, s.w);
            }
            tv[n] = s;
            if (MODE == 1) {
                float pr = s.x * vc[n].x;
                pr = fmaf(s.y, vc[n].y, pr);
                pr = fmaf(s.z, vc[n].z, pr);
                pr = fmaf(s.w, vc[n].w, pr);
                pr = qp_add<0xB1>(pr);   // xor 1 within quad
                pr = qp_add<0x4E>(pr);   // xor 2 -> full dot over d in all 4 lanes
                lg[n] = pr;
            }
        }

        if (MODE == 0) {
            // c uniform (softmax of zeros) -> 0.1 scale applied in reduce
#pragma unroll
            for (int n = 0; n < N_; ++n) {
                acc[n].x += tv[n].x; acc[n].y += tv[n].y;
                acc[n].z += tv[n].z; acc[n].w += tv[n].w;
            }
        } else {
            float m = lg[0];
#pragma unroll
            for (int n = 1; n < N_; ++n) m = fmaxf(m, lg[n]);
            float se = 0.f;
#pragma unroll
            for (int n = 0; n < N_; ++n) { lg[n] = __expf(lg[n] - m); se += lg[n]; }
            float inv = 1.f / se;
#pragma unroll
            for (int n = 0; n < N_; ++n) {
                float cn = lg[n] * inv;
                acc[n].x = fmaf(cn, tv[n].x, acc[n].x);
                acc[n].y = fmaf(cn, tv[n].y, acc[n].y);
                acc[n].z = fmaf(cn, tv[n].z, acc[n].z);
                acc[n].w = fmaf(cn, tv[n].w, acc[n].w);
            }
        }
    }

    // Each thread owns distinct (b, n, dq*4..+3) -> 10 dwordx4 stores, coalesced per quad.
    float* __restrict__ po = part + (size_t)blockIdx.x * BND_ + b * ND_ + dq * 4;
#pragma unroll
    for (int n = 0; n < N_; ++n)
        *(float4*)(po + n * D_) = acc[n];
}

// Parallel-wide reduce: grid 640 x 256. Block handles 16 outputs k; 16 threads
// per k (tp) each sum rows/16 partials with coalesced loads (lanes 0..15 are
// consecutive k). Tree: shfl over tp within wave, LDS across waves.
__global__ __launch_bounds__(256)
void digitcaps_reduce(const float* __restrict__ part, int rows,
                      float scale, int mode,
                      float* __restrict__ Vc, float* __restrict__ out)
{
    __shared__ float sm[4][16];
    const int t = threadIdx.x;
    const int kk = t & 15;
    const int tp = t >> 4;                // 0..15
    const int k = blockIdx.x * 16 + kk;

    float s = 0.f;
    const int steps = rows >> 4;          // rows/16 per tp-thread
    const float* __restrict__ p0 = part + (size_t)tp * BND_ + k;
    const size_t stride = (size_t)16 * BND_;
#pragma unroll 8
    for (int j = 0; j < steps; ++j)
        s += p0[(size_t)j * stride];

    // reduce tp within wave: wave w holds tp in {4w..4w+3}
    s += __shfl_down(s, 32);
    s += __shfl_down(s, 16);
    if ((t & 63) < 16) sm[t >> 6][kk] = s;   // lane tp==4w writes wave-group sum
    __syncthreads();

    if (t < 16) {
        float tot = (sm[0][t] + sm[1][t]) + (sm[2][t] + sm[3][t]);
        tot *= scale;
        float sq = tot * tot;
        float v = tot * (sq / ((1.f + sq) * sqrtf(sq + EPS_)));
        int ko = blockIdx.x * 16 + t;         // = b*160 + n*16 + d natural layout
        if (mode == 0)      Vc[ko] = v;       // after iter 0: Vc = v0
        else if (mode == 1) Vc[ko] += v;      // after iter 1: Vc = v0 + v1
        else                out[ko] = v;      // final output [B,N,1,D]
    }
}

extern "C" void kernel_launch(void* const* d_in, const int* in_sizes, int n_in,
                              void* d_out, int out_size, void* d_ws, size_t ws_size,
                              hipStream_t stream)
{
    const float* x = (const float*)d_in[0];   // [64, 4096, 8] f32
    const float* W = (const float*)d_in[1];   // [4096, 10, 8, 16] f32
    float* out = (float*)d_out;               // [64, 10, 1, 16] f32

    // rows = pass grid size = partial width. 1024 (IPB=4) preferred; 512 fallback.
    size_t need1024 = ((size_t)1024 * BND_ + BND_) * sizeof(float);
    int rows = (ws_size >= need1024) ? 1024 : 512;

    float* part = (float*)d_ws;
    float* Vc   = part + (size_t)rows * BND_;

    dim3 blk(256), grid(rows), rgrid(BND_ / 16);

    for (int pass = 0; pass < 3; ++pass) {
        if (rows == 1024) {
            if (pass == 0)
                digitcaps_pass<0, 4><<<grid, blk, 0, stream>>>(x, W, nullptr, part);
            else
                digitcaps_pass<1, 4><<<grid, blk, 0, stream>>>(x, W, Vc, part);
        } else {
            if (pass == 0)
                digitcaps_pass<0, 8><<<grid, blk, 0, stream>>>(x, W, nullptr, part);
            else
                digitcaps_pass<1, 8><<<grid, blk, 0, stream>>>(x, W, Vc, part);
        }
        digitcaps_reduce<<<rgrid, blk, 0, stream>>>(part, rows,
                                                    pass == 0 ? 0.1f : 1.0f, pass, Vc, out);
    }
}

// Round 6
// 204.609 us; speedup vs baseline: 1.8735x; 1.8735x over previous
//
#include <hip/hip_runtime.h>
#include <math.h>

#define B_ 64
#define I_ 4096
#define P_ 8      // Din
#define N_ 10
#define D_ 16
#define ND_ 160   // N*D
#define BND_ (B_*ND_)   // 10240
#define EPS_ 1e-7f

// DPP add on the VALU pipe (zero DS-pipe traffic — round 4 was DS-bound from
// 160 ds_bpermute/wave-il; round 5 proved the DS-free layout but broke latency
// hiding). ctrl: 0xB1 quad_perm [1,0,3,2] (xor1), 0x4E quad_perm [2,3,0,1]
// (xor2), 0x124 row_ror:4, 0x128 row_ror:8 (rows = 16 lanes on CDNA).
template<int CTRL>
__device__ __forceinline__ float dpp_add(float v) {
    int r = __builtin_amdgcn_update_dpp(0, __float_as_int(v), CTRL, 0xF, 0xF, true);
    return v + __int_as_float(r);
}
// After xor1+xor2 each quad's 4 lanes hold the quad sum; ror:4 then ror:8
// accumulate the other three quads -> every lane of the 16-lane row has the
// full sum over d. 4 VALU ops total, no LDS.
__device__ __forceinline__ float row16_sum(float v) {
    v = dpp_add<0xB1>(v);
    v = dpp_add<0x4E>(v);
    v = dpp_add<0x124>(v);
    v = dpp_add<0x128>(v);
    return v;
}

// Lane mapping (round-4 proven): lane = g*16 + d, g = b-subgroup (0..3),
// d = output dim (0..15) — d spans exactly one DPP row. Wave w covers
// b in {w*16..w*16+15} via 4 bs sub-iterations.
// Per il: hoist all 80 scalar W loads into wr[] (latency hiding — round 5
// showed interleaved float4 W loads stall at 7.7% VALUBusy), then ~800 VALU
// ops of compute. u_hat tv[n] computed once per (b,i), reused for logits
// (row16_sum) and accumulation.
//
// __launch_bounds__(256, 2): measured 116 VGPR / no spill. Tighter bounds
// (256,4) forced VGPR=64 -> 350 MB/pass scratch spill. DO NOT tighten.
// Occupancy: 116 VGPR -> 4 waves/SIMD; LDS 40960 -> 4 blocks/CU; grid 1024.
template<int MODE, int IPB>
__global__ __launch_bounds__(256, 2)
void digitcaps_pass(const float* __restrict__ x, const float* __restrict__ W,
                    const float* __restrict__ Vc, float* __restrict__ part)
{
    __shared__ float vsh[(MODE == 1) ? BND_ : 64];
    const int t = threadIdx.x;
    const int lane = t & 63;
    const int w = t >> 6;        // wave 0..3
    const int d = lane & 15;
    const int g = lane >> 4;     // 0..3

    if (MODE == 1) {
        // Vc natural layout [b][n][d] == vsh layout; straight coalesced copy.
        for (int k = t; k < BND_; k += 256) vsh[k] = Vc[k];
        __syncthreads();
    }

    float acc[4][N_];
#pragma unroll
    for (int bs = 0; bs < 4; ++bs)
#pragma unroll
        for (int n = 0; n < N_; ++n) acc[bs][n] = 0.f;

    const int i0 = blockIdx.x * IPB;

#pragma unroll
    for (int il = 0; il < IPB; ++il) {
        const int i = i0 + il;
        const float* __restrict__ Wi = W + (size_t)i * (N_ * P_ * D_) + d;

        float wr[N_ * P_];
#pragma unroll
        for (int n = 0; n < N_; ++n)
#pragma unroll
            for (int p = 0; p < P_; ++p)
                wr[n * P_ + p] = Wi[(n * P_ + p) * D_];   // 64B-contiguous per 16 lanes

#pragma unroll
        for (int bs = 0; bs < 4; ++bs) {
            const int b = w * 16 + bs * 4 + g;
            float xv[P_];
            {
                const float4* xp = (const float4*)(x + ((size_t)b * I_ + i) * P_);
                float4 a0 = xp[0], a1 = xp[1];
                xv[0]=a0.x; xv[1]=a0.y; xv[2]=a0.z; xv[3]=a0.w;
                xv[4]=a1.x; xv[5]=a1.y; xv[6]=a1.z; xv[7]=a1.w;
            }

            float tv[N_];   // u_hat[b,i,n,d] for this lane's d
#pragma unroll
            for (int n = 0; n < N_; ++n) {
                float s = 0.f;
#pragma unroll
                for (int p = 0; p < P_; ++p)
                    s = fmaf(xv[p], wr[n * P_ + p], s);
                tv[n] = s;
            }

            if (MODE == 0) {
                // c uniform (softmax of zeros) -> 0.1 scale applied in reduce
#pragma unroll
                for (int n = 0; n < N_; ++n) acc[bs][n] += tv[n];
            } else {
                float lg[N_];
#pragma unroll
                for (int n = 0; n < N_; ++n)
                    lg[n] = row16_sum(tv[n] * vsh[b * ND_ + n * D_ + d]);
                float m = lg[0];
#pragma unroll
                for (int n = 1; n < N_; ++n) m = fmaxf(m, lg[n]);
                float se = 0.f;
#pragma unroll
                for (int n = 0; n < N_; ++n) { lg[n] = __expf(lg[n] - m); se += lg[n]; }
                float inv = 1.f / se;
#pragma unroll
                for (int n = 0; n < N_; ++n)
                    acc[bs][n] = fmaf(lg[n] * inv, tv[n], acc[bs][n]);
            }
        }
    }

    // Each thread owns distinct (b,n,d) -> straight stores, no intra-block reduce.
    float* __restrict__ po = part + (size_t)blockIdx.x * BND_;
#pragma unroll
    for (int bs = 0; bs < 4; ++bs) {
        const int b = w * 16 + bs * 4 + g;
#pragma unroll
        for (int n = 0; n < N_; ++n)
            po[b * ND_ + n * D_ + d] = acc[bs][n];
    }
}

// Parallel-wide reduce: grid 640 x 256. Block handles 16 outputs k; 16 threads
// per k (tp) each sum rows/16 partials with coalesced loads (lanes 0..15 are
// consecutive k). Tree: shfl over tp within wave, LDS across waves.
__global__ __launch_bounds__(256)
void digitcaps_reduce(const float* __restrict__ part, int rows,
                      float scale, int mode,
                      float* __restrict__ Vc, float* __restrict__ out)
{
    __shared__ float sm[4][16];
    const int t = threadIdx.x;
    const int kk = t & 15;
    const int tp = t >> 4;                // 0..15
    const int k = blockIdx.x * 16 + kk;

    float s = 0.f;
    const int steps = rows >> 4;          // rows/16 per tp-thread
    const float* __restrict__ p0 = part + (size_t)tp * BND_ + k;
    const size_t stride = (size_t)16 * BND_;
#pragma unroll 8
    for (int j = 0; j < steps; ++j)
        s += p0[(size_t)j * stride];

    // reduce tp within wave: wave w holds tp in {4w..4w+3}
    s += __shfl_down(s, 32);
    s += __shfl_down(s, 16);
    if ((t & 63) < 16) sm[t >> 6][kk] = s;   // lane tp==4w writes wave-group sum
    __syncthreads();

    if (t < 16) {
        float tot = (sm[0][t] + sm[1][t]) + (sm[2][t] + sm[3][t]);
        tot *= scale;
        float sq = tot * tot;
        float v = tot * (sq / ((1.f + sq) * sqrtf(sq + EPS_)));
        int ko = blockIdx.x * 16 + t;         // = b*160 + n*16 + d natural layout
        if (mode == 0)      Vc[ko] = v;       // after iter 0: Vc = v0
        else if (mode == 1) Vc[ko] += v;      // after iter 1: Vc = v0 + v1
        else                out[ko] = v;      // final output [B,N,1,D]
    }
}

extern "C" void kernel_launch(void* const* d_in, const int* in_sizes, int n_in,
                              void* d_out, int out_size, void* d_ws, size_t ws_size,
                              hipStream_t stream)
{
    const float* x = (const float*)d_in[0];   // [64, 4096, 8] f32
    const float* W = (const float*)d_in[1];   // [4096, 10, 8, 16] f32
    float* out = (float*)d_out;               // [64, 10, 1, 16] f32

    // rows = pass grid size = partial width. 1024 (IPB=4) preferred; 512 fallback.
    size_t need1024 = ((size_t)1024 * BND_ + BND_) * sizeof(float);
    int rows = (ws_size >= need1024) ? 1024 : 512;

    float* part = (float*)d_ws;
    float* Vc   = part + (size_t)rows * BND_;

    dim3 blk(256), grid(rows), rgrid(BND_ / 16);

    for (int pass = 0; pass < 3; ++pass) {
        if (rows == 1024) {
            if (pass == 0)
                digitcaps_pass<0, 4><<<grid, blk, 0, stream>>>(x, W, nullptr, part);
            else
                digitcaps_pass<1, 4><<<grid, blk, 0, stream>>>(x, W, Vc, part);
        } else {
            if (pass == 0)
                digitcaps_pass<0, 8><<<grid, blk, 0, stream>>>(x, W, nullptr, part);
            else
                digitcaps_pass<1, 8><<<grid, blk, 0, stream>>>(x, W, Vc, part);
        }
        digitcaps_reduce<<<rgrid, blk, 0, stream>>>(part, rows,
                                                    pass == 0 ? 0.1f : 1.0f, pass, Vc, out);
    }
}